// Round 9
// baseline (890.491 us; speedup 1.0000x reference)
//
#include <hip/hip_runtime.h>
#include <math.h>

// EmmaAttention forward: out = his_x * (p/t) + x * (q/t), per (n,h) row.
//   beta = clip(1 - inv_w*agg_n[n], 0, 1)
//   mm   = max(max_a, his_m)
//   p    = exp(his_m - mm) * beta   (NaN -> exp(-inf)=0)
//   q    = exp(max_a - mm)          (NaN -> 0)
//   t    = max(p + q, 1.0)
// Memory-bound: ~1.24 GB moved per call -> ~197 us floor at 6.3 TB/s.
//
// R9 = R8 with the compile fix: __builtin_nontemporal_load/store requires a
// native clang vector type, not HIP's float4 class. Use
// ext_vector_type(4) float (bit-identical, same dwordx4 codegen).
//  - grid-stride loop, 2048 blocks (256 CU x 8): amortizes wave setup /
//    row math over ~49 vec4s per thread, no 400k-wave tail.
//  - nontemporal loads for x/his_x and nontemporal store for out: these
//    1.23 GB streams are touched once and only thrash L2; keep L2 for the
//    16x-reused per-row scalars (max_a/his_m/agg_n).

#define NN 200000
#define HH 8
#define DD 64
#define N_ROWS   (NN * HH)               // 1,600,000
#define VEC_PER_ROW (DD / 4)             // 16
#define TOTAL_V4 (N_ROWS * VEC_PER_ROW)  // 25,600,000

typedef float f32x4 __attribute__((ext_vector_type(4)));

__global__ __launch_bounds__(256) void emma_fwd_kernel(
    const float* __restrict__ x,
    const float* __restrict__ max_a,
    const float* __restrict__ his_x,
    const float* __restrict__ his_m,
    const float* __restrict__ agg_n,
    const float* __restrict__ inv_w,
    float* __restrict__ out)
{
    const float iw = inv_w[0];   // uniform -> scalar load, hoisted

    const f32x4* __restrict__ x4  = reinterpret_cast<const f32x4*>(x);
    const f32x4* __restrict__ hx4 = reinterpret_cast<const f32x4*>(his_x);
    f32x4*       __restrict__ o4  = reinterpret_cast<f32x4*>(out);

    const unsigned stride = gridDim.x * blockDim.x;   // 524,288
    unsigned tid = blockIdx.x * blockDim.x + threadIdx.x;

    #pragma unroll 2
    for (; tid < TOTAL_V4; tid += stride) {
        const unsigned row = tid >> 4;        // n*H + h   (16 vec4 per row)
        const unsigned n   = row >> 3;        // H = 8

        // Per-row scalars: reused by 16 consecutive lanes -> cached loads.
        const float ma = max_a[row];
        const float hm = his_m[row];
        const float an = agg_n[n];

        float beta = 1.0f - iw * an;
        beta = fminf(fmaxf(beta, 0.0f), 1.0f);

        const float mm = fmaxf(ma, hm);
        const float dp = hm - mm;
        const float dq = ma - mm;
        // jnp.nan_to_num(diff, nan=-inf) -> exp becomes 0 on NaN
        float p = isnan(dp) ? 0.0f : expf(dp);
        float q = isnan(dq) ? 0.0f : expf(dq);
        p *= beta;

        float t = p + q;
        t = fmaxf(t, 1.0f);
        const float rt = 1.0f / t;
        p *= rt;
        q *= rt;

        // Streamed once -> nontemporal (bypass L2 allocation).
        const f32x4 xv = __builtin_nontemporal_load(&x4[tid]);
        const f32x4 hv = __builtin_nontemporal_load(&hx4[tid]);
        f32x4 ov;
        ov.x = hv.x * p + xv.x * q;
        ov.y = hv.y * p + xv.y * q;
        ov.z = hv.z * p + xv.z * q;
        ov.w = hv.w * p + xv.w * q;
        __builtin_nontemporal_store(ov, &o4[tid]);
    }
}

extern "C" void kernel_launch(void* const* d_in, const int* in_sizes, int n_in,
                              void* d_out, int out_size, void* d_ws, size_t ws_size,
                              hipStream_t stream) {
    const float* x     = (const float*)d_in[0];
    const float* max_a = (const float*)d_in[1];
    const float* his_x = (const float*)d_in[2];
    const float* his_m = (const float*)d_in[3];
    const float* agg_n = (const float*)d_in[4];
    const float* inv_w = (const float*)d_in[5];
    float* out = (float*)d_out;

    const int block = 256;
    const int grid  = 2048;   // 256 CUs x 8 blocks/CU, grid-stride loop
    emma_fwd_kernel<<<grid, block, 0, stream>>>(x, max_a, his_x, his_m,
                                                agg_n, inv_w, out);
}